// Round 2
// baseline (154.471 us; speedup 1.0000x reference)
//
#include <hip/hip_runtime.h>
#include <hip/hip_bf16.h>
#include <cstdint>
#include <cstddef>

// Problem constants (fixed by the reference: anchor/positive [4096,512] f32, labels [4096] i32)
constexpr int BN = 4096;   // batch
constexpr int DN = 512;    // feature dim
constexpr int NT = BN / 128;          // 32 tiles per dim
constexpr float MARGIN = 0.2f;
constexpr uint32_t INF_U = 0x7f800000u;   // +inf bits; positive-float order == uint order

typedef __attribute__((ext_vector_type(8))) short short8;     // 8 bf16 = 4 VGPRs (MFMA A/B frag)
typedef __attribute__((ext_vector_type(4))) float float4v;    // MFMA C/D frag

// ---------------------------------------------------------------------------
// Kernel 1: per-row stats + bf16 cast of anchor + init of min arrays.
// One wave per row (4 rows / 256-thread block). Lane l owns elems [8l, 8l+8).
// dap = SQUARED anchor-positive distance (as in the reference).
// ---------------------------------------------------------------------------
__global__ __launch_bounds__(256) void prep_kernel(
    const float* __restrict__ anchor,
    const float* __restrict__ positive,
    uint16_t* __restrict__ Abf,        // [BN][DN] bf16 bits
    float* __restrict__ sqn,           // [BN] ||a_i||^2
    float* __restrict__ dap,           // [BN] squared anchor-positive dist
    uint32_t* __restrict__ min_all,    // [BN] +inf-initialized (min over d2)
    uint32_t* __restrict__ min_larger) // [BN] +inf-initialized (min over d2)
{
    const int tid  = threadIdx.x;
    const int wave = tid >> 6;
    const int lane = tid & 63;
    const int row  = blockIdx.x * 4 + wave;

    const float4* arow = (const float4*)(anchor   + (size_t)row * DN);
    const float4* prow = (const float4*)(positive + (size_t)row * DN);

    float4 av0 = arow[lane * 2 + 0], av1 = arow[lane * 2 + 1];
    float4 pv0 = prow[lane * 2 + 0], pv1 = prow[lane * 2 + 1];

    float a[8] = {av0.x, av0.y, av0.z, av0.w, av1.x, av1.y, av1.z, av1.w};
    float p[8] = {pv0.x, pv0.y, pv0.z, pv0.w, pv1.x, pv1.y, pv1.z, pv1.w};

    float s = 0.f, d = 0.f;
    union { uint16_t u[8]; uint4 v; } pk;
    #pragma unroll
    for (int i = 0; i < 8; ++i) {
        s += a[i] * a[i];
        float dx = a[i] - p[i];
        d += dx * dx;
        uint32_t ub = __float_as_uint(a[i]);               // RNE f32 -> bf16
        pk.u[i] = (uint16_t)((ub + 0x7fffu + ((ub >> 16) & 1u)) >> 16);
    }

    ((uint4*)(Abf + (size_t)row * DN))[lane] = pk.v;       // 16B coalesced store

    #pragma unroll
    for (int off = 32; off; off >>= 1) {
        s += __shfl_xor(s, off);
        d += __shfl_xor(d, off);
    }
    if (lane == 0) {
        sqn[row] = s;
        dap[row] = d;
        min_all[row]    = INF_U;
        min_larger[row] = INF_U;
    }
}

// ---------------------------------------------------------------------------
// Kernel 2: upper-triangular 128x128 tiles of S = A·A^T (bf16 MFMA 16x16x32),
// register-prefetch pipeline (BK=64, 8 k-iters), XOR-swizzled LDS (conflict-
// free b128 read+write), fused epilogue on SQUARED distances with dual-side
// (row and column) masked-min updates via uint atomicMin.
// 256 threads = 4 waves in a 2x2 grid; each wave computes 64x64 via 4x4 MFMAs.
// ---------------------------------------------------------------------------
__global__ __launch_bounds__(256) void gram_kernel(
    const uint16_t* __restrict__ Abf,
    const float* __restrict__ sqn,
    const float* __restrict__ dap,
    const int* __restrict__ labels,
    uint32_t* __restrict__ min_all,
    uint32_t* __restrict__ min_larger)
{
    __shared__ uint16_t Abuf[128 * 64];   // 16 KB, row stride 64 elem = 128 B = 32 banks
    __shared__ uint16_t Bbuf[128 * 64];   // 16 KB

    // triangular decode: blockIdx.x -> (bi, bj) with bi <= bj
    int t = blockIdx.x, bi = 0, rem = NT;
    while (t >= rem) { t -= rem; ++bi; --rem; }
    const int bj = bi + t;
    const bool offdiag = (bi != bj);
    const int rowBase = bi * 128;
    const int colBase = bj * 128;

    const int tid  = threadIdx.x;
    const int wave = tid >> 6;
    const int lane = tid & 63;
    const int wi   = wave >> 1;       // wave row in 2x2 grid
    const int wj   = wave & 1;        // wave col
    const int quad = lane >> 4;
    const int l15  = lane & 15;

    // Staging map: tile = 128 rows x 8 chunks of 16B. Thread handles linear
    // chunks l = tid + i*256: row sr = l>>3, global chunk sc = l&7,
    // LDS slot sp = sc ^ (sr&7)  (XOR swizzle; conflict-free, see derivation).
    int sr[4], sc[4], sp[4];
    #pragma unroll
    for (int i = 0; i < 4; ++i) {
        int l = tid + i * 256;
        sr[i] = l >> 3; sc[i] = l & 7; sp[i] = sc[i] ^ (sr[i] & 7);
    }

    uint4 aS[4], bS[4];
    auto prefetch = [&](int k0) {
        #pragma unroll
        for (int i = 0; i < 4; ++i) {
            aS[i] = *(const uint4*)(Abf + (size_t)(rowBase + sr[i]) * DN + k0 + sc[i] * 8);
            bS[i] = *(const uint4*)(Abf + (size_t)(colBase + sr[i]) * DN + k0 + sc[i] * 8);
        }
    };
    prefetch(0);

    float4v acc[4][4];
    #pragma unroll
    for (int i = 0; i < 4; ++i)
        #pragma unroll
        for (int j = 0; j < 4; ++j)
            acc[i][j] = (float4v){0.f, 0.f, 0.f, 0.f};

    for (int kt = 0; kt < DN / 64; ++kt) {
        __syncthreads();              // readers of previous tile done
        #pragma unroll
        for (int i = 0; i < 4; ++i) {
            *(uint4*)(Abuf + sr[i] * 64 + sp[i] * 8) = aS[i];   // waits vmcnt for own data
            *(uint4*)(Bbuf + sr[i] * 64 + sp[i] * 8) = bS[i];
        }
        __syncthreads();              // LDS tiles visible
        if (kt < DN / 64 - 1) prefetch((kt + 1) * 64);   // overlaps reads+MFMA below

        #pragma unroll
        for (int kk = 0; kk < 2; ++kk) {
            short8 af[4], bfr[4];
            #pragma unroll
            for (int mi = 0; mi < 4; ++mi) {
                int r = wi * 64 + mi * 16 + l15;
                int p = (kk * 4 + quad) ^ (r & 7);
                af[mi] = *(const short8*)(Abuf + r * 64 + p * 8);
            }
            #pragma unroll
            for (int mj = 0; mj < 4; ++mj) {
                int r = wj * 64 + mj * 16 + l15;
                int p = (kk * 4 + quad) ^ (r & 7);
                bfr[mj] = *(const short8*)(Bbuf + r * 64 + p * 8);
            }
            #pragma unroll
            for (int mi = 0; mi < 4; ++mi)
                #pragma unroll
                for (int mj = 0; mj < 4; ++mj)
                    acc[mi][mj] = __builtin_amdgcn_mfma_f32_16x16x32_bf16(
                        af[mi], bfr[mj], acc[mi][mj], 0, 0, 0);
        }
    }

    // ---- epilogue: squared distances, dual-side masked mins ----
    const float INFF = __uint_as_float(INF_U);
    float sqj[4], dapj2[4]; int labj[4];
    #pragma unroll
    for (int mj = 0; mj < 4; ++mj) {
        int col = colBase + wj * 64 + mj * 16 + l15;   // C/D col = lane&15
        sqj[mj]  = sqn[col];
        labj[mj] = labels[col];
        float dj = dap[col];
        dapj2[mj] = dj * dj;
    }
    float cAll[4], cLarger[4];
    #pragma unroll
    for (int mj = 0; mj < 4; ++mj) { cAll[mj] = INFF; cLarger[mj] = INFF; }

    #pragma unroll
    for (int mi = 0; mi < 4; ++mi) {
        #pragma unroll
        for (int r = 0; r < 4; ++r) {
            int row = rowBase + wi * 64 + mi * 16 + quad * 4 + r;  // C/D row = quad*4+reg
            float sqi  = sqn[row];
            int   li   = labels[row];
            float dapi = dap[row];
            float dapi2 = dapi * dapi;
            float mAll = INFF, mLarger = INFF;
            #pragma unroll
            for (int mj = 0; mj < 4; ++mj) {
                float d2 = sqi + sqj[mj] - 2.0f * acc[mi][mj][r];
                d2 = d2 > 0.f ? d2 : 0.f;
                if (labj[mj] != li) {
                    mAll = fminf(mAll, d2);
                    if (d2 > dapi2) mLarger = fminf(mLarger, d2);
                    if (offdiag) {
                        cAll[mj] = fminf(cAll[mj], d2);
                        if (d2 > dapj2[mj]) cLarger[mj] = fminf(cLarger[mj], d2);
                    }
                }
            }
            // min across the 16 lanes of this quad (they share `row`, cover 64 cols)
            #pragma unroll
            for (int off = 1; off < 16; off <<= 1) {
                mAll    = fminf(mAll,    __shfl_xor(mAll, off));
                mLarger = fminf(mLarger, __shfl_xor(mLarger, off));
            }
            if (l15 == 0) {
                atomicMin(&min_all[row],    __float_as_uint(mAll));
                atomicMin(&min_larger[row], __float_as_uint(mLarger));
            }
        }
    }
    if (offdiag) {
        // col j = colBase + wj*64 + mj*16 + l15 is shared by the 4 quads
        #pragma unroll
        for (int mj = 0; mj < 4; ++mj) {
            float a0 = cAll[mj], l0 = cLarger[mj];
            a0 = fminf(a0, __shfl_xor(a0, 16)); l0 = fminf(l0, __shfl_xor(l0, 16));
            a0 = fminf(a0, __shfl_xor(a0, 32)); l0 = fminf(l0, __shfl_xor(l0, 32));
            if (quad == 0) {
                int col = colBase + wj * 64 + mj * 16 + l15;
                atomicMin(&min_all[col],    __float_as_uint(a0));
                atomicMin(&min_larger[col], __float_as_uint(l0));
            }
        }
    }
}

// ---------------------------------------------------------------------------
// Kernel 3: semi-hard select (on d2), sqrt, hinge, mean. One 256-thread block.
// ---------------------------------------------------------------------------
__global__ __launch_bounds__(256) void finalize_kernel(
    const float* __restrict__ dap,
    const uint32_t* __restrict__ min_all,
    const uint32_t* __restrict__ min_larger,
    float* __restrict__ out)
{
    const int tid = threadIdx.x;
    float s = 0.f;
    for (int i = tid; i < BN; i += 256) {
        uint32_t mlu = min_larger[i];
        float dan2 = (mlu != INF_U) ? __uint_as_float(mlu) : __uint_as_float(min_all[i]);
        float dan = sqrtf(dan2);
        float l = dap[i] - dan + MARGIN;
        s += l > 0.f ? l : 0.f;
    }
    #pragma unroll
    for (int off = 32; off; off >>= 1) s += __shfl_xor(s, off);
    __shared__ float wsum[4];
    if ((tid & 63) == 0) wsum[tid >> 6] = s;
    __syncthreads();
    if (tid == 0) out[0] = (wsum[0] + wsum[1] + wsum[2] + wsum[3]) * (1.0f / BN);
}

// ---------------------------------------------------------------------------
extern "C" void kernel_launch(void* const* d_in, const int* in_sizes, int n_in,
                              void* d_out, int out_size, void* d_ws, size_t ws_size,
                              hipStream_t stream) {
    const float* anchor   = (const float*)d_in[0];
    const float* positive = (const float*)d_in[1];
    const int*   labels   = (const int*)d_in[2];
    float* out = (float*)d_out;

    // Workspace layout (needs ~4.26 MB)
    uint8_t* ws = (uint8_t*)d_ws;
    uint16_t* Abf        = (uint16_t*)ws;                          // 4 MB bf16 anchor
    float*    sqn        = (float*)(ws + (size_t)BN * DN * 2);     // 16 KB
    float*    dap        = sqn + BN;                               // 16 KB
    uint32_t* min_all    = (uint32_t*)(dap + BN);                  // 16 KB
    uint32_t* min_larger = min_all + BN;                           // 16 KB

    prep_kernel<<<BN / 4, 256, 0, stream>>>(anchor, positive, Abf, sqn, dap, min_all, min_larger);
    gram_kernel<<<NT * (NT + 1) / 2, 256, 0, stream>>>(Abf, sqn, dap, labels, min_all, min_larger);
    finalize_kernel<<<1, 256, 0, stream>>>(dap, min_all, min_larger, out);
}

// Round 3
// 123.089 us; speedup vs baseline: 1.2550x; 1.2550x over previous
//
#include <hip/hip_runtime.h>
#include <hip/hip_bf16.h>
#include <cstdint>
#include <cstddef>

// Problem constants (fixed by the reference: anchor/positive [4096,512] f32, labels [4096] i32)
constexpr int BN = 4096;   // batch
constexpr int DN = 512;    // feature dim
constexpr int NT = BN / 128;              // 32 tiles per dim
constexpr int NBLK = NT * (NT + 1) / 2;   // 528 triangular tile-pairs
constexpr float MARGIN = 0.2f;
constexpr uint32_t INF_U = 0x7f800000u;   // +inf bits; positive-float order == uint order

typedef __attribute__((ext_vector_type(8))) short short8;     // 8 bf16 = 4 VGPRs (MFMA A/B frag)
typedef __attribute__((ext_vector_type(4))) float float4v;    // MFMA C/D frag

#define AS1(p) ((const __attribute__((address_space(1))) void*)(p))
#define AS3(p) ((__attribute__((address_space(3))) void*)(p))

// ---------------------------------------------------------------------------
// Kernel 1: per-row stats + bf16 cast of anchor + init of min arrays + counter.
// One wave per row (4 rows / 256-thread block). Lane l owns elems [8l, 8l+8).
// dap = SQUARED anchor-positive distance (as in the reference).
// ---------------------------------------------------------------------------
__global__ __launch_bounds__(256) void prep_kernel(
    const float* __restrict__ anchor,
    const float* __restrict__ positive,
    uint16_t* __restrict__ Abf,        // [BN][DN] bf16 bits
    float* __restrict__ sqn,           // [BN] ||a_i||^2
    float* __restrict__ dap,           // [BN] squared anchor-positive dist
    uint32_t* __restrict__ min_all,    // [BN] +inf-initialized (min over d2)
    uint32_t* __restrict__ min_larger, // [BN] +inf-initialized (min over d2)
    uint32_t* __restrict__ done_count) // single counter, zeroed here
{
    const int tid  = threadIdx.x;
    const int wave = tid >> 6;
    const int lane = tid & 63;
    const int row  = blockIdx.x * 4 + wave;

    if (blockIdx.x == 0 && tid == 0) *done_count = 0;

    const float4* arow = (const float4*)(anchor   + (size_t)row * DN);
    const float4* prow = (const float4*)(positive + (size_t)row * DN);

    float4 av0 = arow[lane * 2 + 0], av1 = arow[lane * 2 + 1];
    float4 pv0 = prow[lane * 2 + 0], pv1 = prow[lane * 2 + 1];

    float a[8] = {av0.x, av0.y, av0.z, av0.w, av1.x, av1.y, av1.z, av1.w};
    float p[8] = {pv0.x, pv0.y, pv0.z, pv0.w, pv1.x, pv1.y, pv1.z, pv1.w};

    float s = 0.f, d = 0.f;
    union { uint16_t u[8]; uint4 v; } pk;
    #pragma unroll
    for (int i = 0; i < 8; ++i) {
        s += a[i] * a[i];
        float dx = a[i] - p[i];
        d += dx * dx;
        uint32_t ub = __float_as_uint(a[i]);               // RNE f32 -> bf16
        pk.u[i] = (uint16_t)((ub + 0x7fffu + ((ub >> 16) & 1u)) >> 16);
    }

    ((uint4*)(Abf + (size_t)row * DN))[lane] = pk.v;       // 16B coalesced store

    #pragma unroll
    for (int off = 32; off; off >>= 1) {
        s += __shfl_xor(s, off);
        d += __shfl_xor(d, off);
    }
    if (lane == 0) {
        sqn[row] = s;
        dap[row] = d;
        min_all[row]    = INF_U;
        min_larger[row] = INF_U;
    }
}

// ---------------------------------------------------------------------------
// Kernel 2: upper-triangular 128x128 tiles of S = A·A^T (bf16 MFMA 16x16x32).
// Staging: global_load_lds width=16 (no staging VGPRs -> no spills), with the
// XOR-8 swizzle expressed on the GLOBAL source address (LDS dest must be
// lane-contiguous): lane fetches chunk (slot ^ row&7) so LDS slot s of row r
// holds global chunk s ^ (r&7). BK=64 -> row stride 128 B -> conflict-free
// b128 reads (0 conflicts measured in round 2).
// Epilogue: squared-distance dual-side masked mins via uint atomicMin.
// Last block (device counter) folds in the finalize: select, sqrt, hinge, mean.
// ---------------------------------------------------------------------------
__global__ __launch_bounds__(256) void gram_kernel(
    const uint16_t* __restrict__ Abf,
    const float* __restrict__ sqn,
    const float* __restrict__ dap,
    const int* __restrict__ labels,
    uint32_t* __restrict__ min_all,
    uint32_t* __restrict__ min_larger,
    uint32_t* __restrict__ done_count,
    float* __restrict__ out)
{
    __shared__ uint16_t Abuf[128 * 64];   // 16 KB, row stride 64 elem = 128 B = 32 banks
    __shared__ uint16_t Bbuf[128 * 64];   // 16 KB

    // triangular decode: blockIdx.x -> (bi, bj) with bi <= bj
    int t = blockIdx.x, bi = 0, rem = NT;
    while (t >= rem) { t -= rem; ++bi; --rem; }
    const int bj = bi + t;
    const bool offdiag = (bi != bj);
    const int rowBase = bi * 128;
    const int colBase = bj * 128;

    const int tid  = threadIdx.x;
    const int wave = tid >> 6;
    const int lane = tid & 63;
    const int wi   = wave >> 1;       // wave row in 2x2 grid
    const int wj   = wave & 1;        // wave col
    const int quad = lane >> 4;
    const int l15  = lane & 15;

    // global_load_lds lane map: one instr = 64 lanes x 16 B = 8 rows x 128 B.
    // lane l -> row r0 + (l>>3), LDS slot (l&7), global chunk (l&7)^(l>>3).
    const int lrow   = lane >> 3;
    const int lchunk = (lane & 7) ^ lrow;        // swizzled source chunk

    float4v acc[4][4];
    #pragma unroll
    for (int i = 0; i < 4; ++i)
        #pragma unroll
        for (int j = 0; j < 4; ++j)
            acc[i][j] = (float4v){0.f, 0.f, 0.f, 0.f};

    for (int kt = 0; kt < DN / 64; ++kt) {
        const int k0 = kt * 64;
        __syncthreads();              // readers of previous tile done
        #pragma unroll
        for (int s = 0; s < 4; ++s) {
            const int r0 = (wave * 4 + s) * 8;   // wave-uniform 8-row slab
            const uint16_t* ga = Abf + (size_t)(rowBase + r0 + lrow) * DN + k0 + lchunk * 8;
            __builtin_amdgcn_global_load_lds(AS1(ga), AS3(Abuf + r0 * 64), 16, 0, 0);
            const uint16_t* gb = Abf + (size_t)(colBase + r0 + lrow) * DN + k0 + lchunk * 8;
            __builtin_amdgcn_global_load_lds(AS1(gb), AS3(Bbuf + r0 * 64), 16, 0, 0);
        }
        __syncthreads();              // drains vmcnt: LDS tiles ready

        #pragma unroll
        for (int kk = 0; kk < 2; ++kk) {
            short8 af[4], bfr[4];
            #pragma unroll
            for (int mi = 0; mi < 4; ++mi) {
                int r = wi * 64 + mi * 16 + l15;
                int p = (kk * 4 + quad) ^ (r & 7);
                af[mi] = *(const short8*)(Abuf + r * 64 + p * 8);
            }
            #pragma unroll
            for (int mj = 0; mj < 4; ++mj) {
                int r = wj * 64 + mj * 16 + l15;
                int p = (kk * 4 + quad) ^ (r & 7);
                bfr[mj] = *(const short8*)(Bbuf + r * 64 + p * 8);
            }
            #pragma unroll
            for (int mi = 0; mi < 4; ++mi)
                #pragma unroll
                for (int mj = 0; mj < 4; ++mj)
                    acc[mi][mj] = __builtin_amdgcn_mfma_f32_16x16x32_bf16(
                        af[mi], bfr[mj], acc[mi][mj], 0, 0, 0);
        }
    }

    // ---- epilogue: squared distances, dual-side masked mins ----
    const float INFF = __uint_as_float(INF_U);
    float sqj[4], dapj2[4]; int labj[4];
    #pragma unroll
    for (int mj = 0; mj < 4; ++mj) {
        int col = colBase + wj * 64 + mj * 16 + l15;   // C/D col = lane&15
        sqj[mj]  = sqn[col];
        labj[mj] = labels[col];
        dapj2[mj] = dap[col];
    }
    float cAll[4], cLarger[4];
    #pragma unroll
    for (int mj = 0; mj < 4; ++mj) { cAll[mj] = INFF; cLarger[mj] = INFF; }

    #pragma unroll
    for (int mi = 0; mi < 4; ++mi) {
        #pragma unroll
        for (int r = 0; r < 4; ++r) {
            int row = rowBase + wi * 64 + mi * 16 + quad * 4 + r;  // C/D row = quad*4+reg
            float sqi   = sqn[row];
            int   li    = labels[row];
            float dapi  = dap[row];          // squared d_ap (threshold)
            float mAll = INFF, mLarger = INFF;
            #pragma unroll
            for (int mj = 0; mj < 4; ++mj) {
                float d2 = sqi + sqj[mj] - 2.0f * acc[mi][mj][r];
                d2 = d2 > 0.f ? d2 : 0.f;
                if (labj[mj] != li) {
                    mAll = fminf(mAll, d2);
                    // reference compares pd (euclidean) > d_ap (squared):
                    // pd > d_ap  <=>  d2 > d_ap^2  (both non-negative)
                    if (d2 > dapi * dapi) mLarger = fminf(mLarger, d2);
                    if (offdiag) {
                        cAll[mj] = fminf(cAll[mj], d2);
                        if (d2 > dapj2[mj] * dapj2[mj]) cLarger[mj] = fminf(cLarger[mj], d2);
                    }
                }
            }
            // min across the 16 lanes of this quad (they share `row`, cover 64 cols)
            #pragma unroll
            for (int off = 1; off < 16; off <<= 1) {
                mAll    = fminf(mAll,    __shfl_xor(mAll, off));
                mLarger = fminf(mLarger, __shfl_xor(mLarger, off));
            }
            if (l15 == 0) {
                atomicMin(&min_all[row],    __float_as_uint(mAll));
                atomicMin(&min_larger[row], __float_as_uint(mLarger));
            }
        }
    }
    if (offdiag) {
        // col j = colBase + wj*64 + mj*16 + l15 is shared by the 4 quads
        #pragma unroll
        for (int mj = 0; mj < 4; ++mj) {
            float a0 = cAll[mj], l0 = cLarger[mj];
            a0 = fminf(a0, __shfl_xor(a0, 16)); l0 = fminf(l0, __shfl_xor(l0, 16));
            a0 = fminf(a0, __shfl_xor(a0, 32)); l0 = fminf(l0, __shfl_xor(l0, 32));
            if (quad == 0) {
                int col = colBase + wj * 64 + mj * 16 + l15;
                atomicMin(&min_all[col],    __float_as_uint(a0));
                atomicMin(&min_larger[col], __float_as_uint(l0));
            }
        }
    }

    // ---- last-block finalize: select, sqrt, hinge, mean ----
    __shared__ bool isLast;
    __syncthreads();                      // all this block's atomics issued & drained
    if (tid == 0) {
        __threadfence();                  // make our mins visible device-wide
        isLast = (atomicAdd(done_count, 1u) == NBLK - 1);
    }
    __syncthreads();
    if (isLast) {
        __threadfence();                  // acquire: see all other blocks' mins
        float s = 0.f;
        for (int i = tid; i < BN; i += 256) {
            uint32_t mlu = __hip_atomic_load(&min_larger[i], __ATOMIC_RELAXED, __HIP_MEMORY_SCOPE_AGENT);
            uint32_t mau = __hip_atomic_load(&min_all[i],    __ATOMIC_RELAXED, __HIP_MEMORY_SCOPE_AGENT);
            float dan2 = (mlu != INF_U) ? __uint_as_float(mlu) : __uint_as_float(mau);
            float l = dap[i] - sqrtf(dan2) + MARGIN;
            s += l > 0.f ? l : 0.f;
        }
        #pragma unroll
        for (int off = 32; off; off >>= 1) s += __shfl_xor(s, off);
        __shared__ float wsum[4];
        if ((tid & 63) == 0) wsum[tid >> 6] = s;
        __syncthreads();
        if (tid == 0) out[0] = (wsum[0] + wsum[1] + wsum[2] + wsum[3]) * (1.0f / BN);
    }
}

// ---------------------------------------------------------------------------
extern "C" void kernel_launch(void* const* d_in, const int* in_sizes, int n_in,
                              void* d_out, int out_size, void* d_ws, size_t ws_size,
                              hipStream_t stream) {
    const float* anchor   = (const float*)d_in[0];
    const float* positive = (const float*)d_in[1];
    const int*   labels   = (const int*)d_in[2];
    float* out = (float*)d_out;

    // Workspace layout (needs ~4.26 MB)
    uint8_t* ws = (uint8_t*)d_ws;
    uint16_t* Abf        = (uint16_t*)ws;                          // 4 MB bf16 anchor
    float*    sqn        = (float*)(ws + (size_t)BN * DN * 2);     // 16 KB
    float*    dap        = sqn + BN;                               // 16 KB
    uint32_t* min_all    = (uint32_t*)(dap + BN);                  // 16 KB
    uint32_t* min_larger = min_all + BN;                           // 16 KB
    uint32_t* done_count = min_larger + BN;                        // 4 B

    prep_kernel<<<BN / 4, 256, 0, stream>>>(anchor, positive, Abf, sqn, dap,
                                            min_all, min_larger, done_count);
    gram_kernel<<<NBLK, 256, 0, stream>>>(Abf, sqn, dap, labels,
                                          min_all, min_larger, done_count, out);
}

// Round 4
// 106.553 us; speedup vs baseline: 1.4497x; 1.1552x over previous
//
#include <hip/hip_runtime.h>
#include <hip/hip_bf16.h>
#include <cstdint>
#include <cstddef>

// Problem constants (fixed by the reference: anchor/positive [4096,512] f32, labels [4096] i32)
constexpr int BN = 4096;   // batch
constexpr int DN = 512;    // feature dim
constexpr int NT = BN / 128;              // 32 tiles per dim
constexpr int NBLK = NT * (NT + 1) / 2;   // 528 triangular tile-pairs
constexpr float MARGIN = 0.2f;
constexpr uint32_t INF_U = 0x7f800000u;   // +inf bits; positive-float order == uint order

typedef __attribute__((ext_vector_type(8))) short short8;     // 8 bf16 = 4 VGPRs (MFMA A/B frag)
typedef __attribute__((ext_vector_type(4))) float float4v;    // MFMA C/D frag

// ---------------------------------------------------------------------------
// Kernel 1: per-row stats + bf16 cast of anchor + init of min arrays + counter.
// One wave per row (4 rows / 256-thread block). Lane l owns elems [8l, 8l+8).
// meta[row] = {||a||^2, d_ap(squared), d_ap^2, label-bits}  (one b128 load later)
// ---------------------------------------------------------------------------
__global__ __launch_bounds__(256) void prep_kernel(
    const float* __restrict__ anchor,
    const float* __restrict__ positive,
    const int* __restrict__ labels,
    uint16_t* __restrict__ Abf,        // [BN][DN] bf16 bits
    float4* __restrict__ meta,         // [BN]
    uint32_t* __restrict__ min_all,    // [BN] +inf-initialized (min over d2)
    uint32_t* __restrict__ min_larger, // [BN] +inf-initialized (min over d2)
    uint32_t* __restrict__ done_count) // single counter, zeroed here
{
    const int tid  = threadIdx.x;
    const int wave = tid >> 6;
    const int lane = tid & 63;
    const int row  = blockIdx.x * 4 + wave;

    if (blockIdx.x == 0 && tid == 0) *done_count = 0;

    const float4* arow = (const float4*)(anchor   + (size_t)row * DN);
    const float4* prow = (const float4*)(positive + (size_t)row * DN);

    float4 av0 = arow[lane * 2 + 0], av1 = arow[lane * 2 + 1];
    float4 pv0 = prow[lane * 2 + 0], pv1 = prow[lane * 2 + 1];

    float a[8] = {av0.x, av0.y, av0.z, av0.w, av1.x, av1.y, av1.z, av1.w};
    float p[8] = {pv0.x, pv0.y, pv0.z, pv0.w, pv1.x, pv1.y, pv1.z, pv1.w};

    float s = 0.f, d = 0.f;
    union { uint16_t u[8]; uint4 v; } pk;
    #pragma unroll
    for (int i = 0; i < 8; ++i) {
        s += a[i] * a[i];
        float dx = a[i] - p[i];
        d += dx * dx;
        uint32_t ub = __float_as_uint(a[i]);               // RNE f32 -> bf16
        pk.u[i] = (uint16_t)((ub + 0x7fffu + ((ub >> 16) & 1u)) >> 16);
    }

    ((uint4*)(Abf + (size_t)row * DN))[lane] = pk.v;       // 16B coalesced store

    #pragma unroll
    for (int off = 32; off; off >>= 1) {
        s += __shfl_xor(s, off);
        d += __shfl_xor(d, off);
    }
    if (lane == 0) {
        meta[row] = (float4){s, d, d * d, __uint_as_float((uint32_t)labels[row])};
        min_all[row]    = INF_U;
        min_larger[row] = INF_U;
    }
}

// ---------------------------------------------------------------------------
// Kernel 2: upper-triangular 128x128 tiles of S = A·A^T (bf16 MFMA 16x16x32).
// Staging: plain uint4 global loads -> immediate ds_write_b128 (loads pipeline;
// NO global_load_lds — its per-wave DMA chain serialized at ~2.2k cyc/instr and
// was the 58 µs wall in rounds 1/3; NO cross-barrier register liveness — that
// spilled in round 2). XOR-8 swizzle on LDS slot (0 conflicts measured).
// BK=64 -> row stride 128 B. Epilogue: squared-distance dual-side masked mins
// via uint atomicMin; meta float4 gives sqn/dap/dap^2/label in one b128 load.
// Last block (device counter) folds in the finalize: select, sqrt, hinge, mean.
// ---------------------------------------------------------------------------
__global__ __launch_bounds__(256, 3) void gram_kernel(
    const uint16_t* __restrict__ Abf,
    const float4* __restrict__ meta,
    uint32_t* __restrict__ min_all,
    uint32_t* __restrict__ min_larger,
    uint32_t* __restrict__ done_count,
    float* __restrict__ out)
{
    __shared__ uint16_t Abuf[128 * 64];   // 16 KB, row stride 64 elem = 128 B = 32 banks
    __shared__ uint16_t Bbuf[128 * 64];   // 16 KB

    // triangular decode: blockIdx.x -> (bi, bj) with bi <= bj
    int t = blockIdx.x, bi = 0, rem = NT;
    while (t >= rem) { t -= rem; ++bi; --rem; }
    const int bj = bi + t;
    const bool offdiag = (bi != bj);
    const int rowBase = bi * 128;
    const int colBase = bj * 128;

    const int tid  = threadIdx.x;
    const int wave = tid >> 6;
    const int lane = tid & 63;
    const int wi   = wave >> 1;       // wave row in 2x2 grid
    const int wj   = wave & 1;        // wave col
    const int quad = lane >> 4;
    const int l15  = lane & 15;

    // Staging map: tile = 128 rows x 8 chunks of 16B. Thread handles linear
    // chunks l = tid + i*256: row sr = l>>3, global chunk sc = l&7,
    // LDS slot sp = sc ^ (sr&7)  (XOR swizzle; 0 conflicts measured R2/R3).
    int sr[4], sc[4], sp[4];
    #pragma unroll
    for (int i = 0; i < 4; ++i) {
        int l = tid + i * 256;
        sr[i] = l >> 3; sc[i] = l & 7; sp[i] = sc[i] ^ (sr[i] & 7);
    }

    float4v acc[4][4];
    #pragma unroll
    for (int i = 0; i < 4; ++i)
        #pragma unroll
        for (int j = 0; j < 4; ++j)
            acc[i][j] = (float4v){0.f, 0.f, 0.f, 0.f};

    for (int kt = 0; kt < DN / 64; ++kt) {
        const int k0 = kt * 64;
        __syncthreads();              // readers of previous tile done
        {
            uint4 st[4];
            #pragma unroll
            for (int i = 0; i < 4; ++i)     // 4 independent loads -> pipeline
                st[i] = *(const uint4*)(Abf + (size_t)(rowBase + sr[i]) * DN + k0 + sc[i] * 8);
            #pragma unroll
            for (int i = 0; i < 4; ++i)
                *(uint4*)(Abuf + sr[i] * 64 + sp[i] * 8) = st[i];
            #pragma unroll
            for (int i = 0; i < 4; ++i)
                st[i] = *(const uint4*)(Abf + (size_t)(colBase + sr[i]) * DN + k0 + sc[i] * 8);
            #pragma unroll
            for (int i = 0; i < 4; ++i)
                *(uint4*)(Bbuf + sr[i] * 64 + sp[i] * 8) = st[i];
        }
        __syncthreads();              // LDS tiles visible

        #pragma unroll
        for (int kk = 0; kk < 2; ++kk) {
            short8 af[4], bfr[4];
            #pragma unroll
            for (int mi = 0; mi < 4; ++mi) {
                int r = wi * 64 + mi * 16 + l15;
                int p = (kk * 4 + quad) ^ (r & 7);
                af[mi] = *(const short8*)(Abuf + r * 64 + p * 8);
            }
            #pragma unroll
            for (int mj = 0; mj < 4; ++mj) {
                int r = wj * 64 + mj * 16 + l15;
                int p = (kk * 4 + quad) ^ (r & 7);
                bfr[mj] = *(const short8*)(Bbuf + r * 64 + p * 8);
            }
            #pragma unroll
            for (int mi = 0; mi < 4; ++mi)
                #pragma unroll
                for (int mj = 0; mj < 4; ++mj)
                    acc[mi][mj] = __builtin_amdgcn_mfma_f32_16x16x32_bf16(
                        af[mi], bfr[mj], acc[mi][mj], 0, 0, 0);
        }
    }

    // ---- epilogue: squared distances, dual-side masked mins ----
    const float INFF = __uint_as_float(INF_U);
    float4 mj_meta[4];
    #pragma unroll
    for (int mj = 0; mj < 4; ++mj)
        mj_meta[mj] = meta[colBase + wj * 64 + mj * 16 + l15];   // C/D col = lane&15

    float cAll[4], cLarger[4];
    #pragma unroll
    for (int mj = 0; mj < 4; ++mj) { cAll[mj] = INFF; cLarger[mj] = INFF; }

    #pragma unroll
    for (int mi = 0; mi < 4; ++mi) {
        #pragma unroll
        for (int r = 0; r < 4; ++r) {
            int row = rowBase + wi * 64 + mi * 16 + quad * 4 + r;  // C/D row = quad*4+reg
            float4 mim = meta[row];          // {sqn, dap, dap^2, label}
            uint32_t li = __float_as_uint(mim.w);
            float mAll = INFF, mLarger = INFF;
            #pragma unroll
            for (int mj = 0; mj < 4; ++mj) {
                float d2 = mim.x + mj_meta[mj].x - 2.0f * acc[mi][mj][r];
                d2 = d2 > 0.f ? d2 : 0.f;
                if (__float_as_uint(mj_meta[mj].w) != li) {
                    mAll = fminf(mAll, d2);
                    // reference: pd (euclidean) > d_ap (squared)  <=>  d2 > dap^2
                    if (d2 > mim.z) mLarger = fminf(mLarger, d2);
                    if (offdiag) {
                        cAll[mj] = fminf(cAll[mj], d2);
                        if (d2 > mj_meta[mj].z) cLarger[mj] = fminf(cLarger[mj], d2);
                    }
                }
            }
            // min across the 16 lanes of this quad (they share `row`, cover 64 cols)
            #pragma unroll
            for (int off = 1; off < 16; off <<= 1) {
                mAll    = fminf(mAll,    __shfl_xor(mAll, off));
                mLarger = fminf(mLarger, __shfl_xor(mLarger, off));
            }
            if (l15 == 0) {
                atomicMin(&min_all[row],    __float_as_uint(mAll));
                atomicMin(&min_larger[row], __float_as_uint(mLarger));
            }
        }
    }
    if (offdiag) {
        // col j = colBase + wj*64 + mj*16 + l15 is shared by the 4 quads
        #pragma unroll
        for (int mj = 0; mj < 4; ++mj) {
            float a0 = cAll[mj], l0 = cLarger[mj];
            a0 = fminf(a0, __shfl_xor(a0, 16)); l0 = fminf(l0, __shfl_xor(l0, 16));
            a0 = fminf(a0, __shfl_xor(a0, 32)); l0 = fminf(l0, __shfl_xor(l0, 32));
            if (quad == 0) {
                int col = colBase + wj * 64 + mj * 16 + l15;
                atomicMin(&min_all[col],    __float_as_uint(a0));
                atomicMin(&min_larger[col], __float_as_uint(l0));
            }
        }
    }

    // ---- last-block finalize: select, sqrt, hinge, mean ----
    __shared__ bool isLast;
    __syncthreads();                      // all this block's atomics issued
    if (tid == 0) {
        __threadfence();                  // make our mins visible device-wide
        isLast = (atomicAdd(done_count, 1u) == NBLK - 1);
    }
    __syncthreads();
    if (isLast) {
        __threadfence();                  // acquire: see all other blocks' mins
        float s = 0.f;
        for (int i = tid; i < BN; i += 256) {
            uint32_t mlu = __hip_atomic_load(&min_larger[i], __ATOMIC_RELAXED, __HIP_MEMORY_SCOPE_AGENT);
            uint32_t mau = __hip_atomic_load(&min_all[i],    __ATOMIC_RELAXED, __HIP_MEMORY_SCOPE_AGENT);
            float dan2 = (mlu != INF_U) ? __uint_as_float(mlu) : __uint_as_float(mau);
            float l = meta[i].y - sqrtf(dan2) + MARGIN;
            s += l > 0.f ? l : 0.f;
        }
        #pragma unroll
        for (int off = 32; off; off >>= 1) s += __shfl_xor(s, off);
        __shared__ float wsum[4];
        if ((tid & 63) == 0) wsum[tid >> 6] = s;
        __syncthreads();
        if (tid == 0) out[0] = (wsum[0] + wsum[1] + wsum[2] + wsum[3]) * (1.0f / BN);
    }
}

// ---------------------------------------------------------------------------
extern "C" void kernel_launch(void* const* d_in, const int* in_sizes, int n_in,
                              void* d_out, int out_size, void* d_ws, size_t ws_size,
                              hipStream_t stream) {
    const float* anchor   = (const float*)d_in[0];
    const float* positive = (const float*)d_in[1];
    const int*   labels   = (const int*)d_in[2];
    float* out = (float*)d_out;

    // Workspace layout (~4.4 MB)
    uint8_t* ws = (uint8_t*)d_ws;
    uint16_t* Abf        = (uint16_t*)ws;                          // 4 MB bf16 anchor
    float4*   meta       = (float4*)(ws + (size_t)BN * DN * 2);    // 64 KB
    uint32_t* min_all    = (uint32_t*)(meta + BN);                 // 16 KB
    uint32_t* min_larger = min_all + BN;                           // 16 KB
    uint32_t* done_count = min_larger + BN;                        // 4 B

    prep_kernel<<<BN / 4, 256, 0, stream>>>(anchor, positive, labels, Abf, meta,
                                            min_all, min_larger, done_count);
    gram_kernel<<<NBLK, 256, 0, stream>>>(Abf, meta, min_all, min_larger, done_count, out);
}